// Round 1
// baseline (411.946 us; speedup 1.0000x reference)
//
#include <hip/hip_runtime.h>

typedef unsigned short u16;
typedef __attribute__((ext_vector_type(8))) short short8;
typedef __attribute__((ext_vector_type(4))) float f32x4;
typedef __attribute__((ext_vector_type(4))) float floatx4;
typedef __attribute__((ext_vector_type(4))) unsigned short ushort4v;
typedef __attribute__((ext_vector_type(8))) unsigned short ushort8v;

#define MFMA(a, b, c) __builtin_amdgcn_mfma_f32_16x16x32_bf16(a, b, c, 0, 0, 0)

__device__ __forceinline__ u16 f2bf(float f) {
    unsigned u = __float_as_uint(f);
    u += 0x7fffu + ((u >> 16) & 1u);   // RNE
    return (u16)(u >> 16);
}

__device__ __forceinline__ void async16(const void* g, void* l) {
    __builtin_amdgcn_global_load_lds(
        (const __attribute__((address_space(1))) void*)g,
        (__attribute__((address_space(3))) void*)l, 16, 0, 0);
}

// ---------------- fp32 -> bf16 convert, float4 vectorized ----------------
__global__ void cvt_bf16(const float* __restrict__ s, u16* __restrict__ d, int n4) {
    int i = blockIdx.x * blockDim.x + threadIdx.x;
    int stride = gridDim.x * blockDim.x;
    for (; i < n4; i += stride) {
        floatx4 v = ((const floatx4*)s)[i];
        ushort4v o;
        o[0] = f2bf(v[0]); o[1] = f2bf(v[1]); o[2] = f2bf(v[2]); o[3] = f2bf(v[3]);
        ((ushort4v*)d)[i] = o;
    }
}

// ---------------- NT GEMM: C[M,N] = A[M,K] * B[N,K]^T (m97 recipe) --------
// 128x128 tile, BK=32, global_load_lds width 16, 2x2 waves, 4x4 acc/wave.
// grid.z selects B-matrix (for fused QKV) and C slice.
template <bool BF16_OUT>
__global__ __launch_bounds__(256) void gemm_nt(
    const u16* __restrict__ A, const u16* __restrict__ B0,
    const u16* __restrict__ B1, const u16* __restrict__ B2,
    void* __restrict__ Cv, int M, int N, int K)
{
    __shared__ u16 As[128 * 32];
    __shared__ u16 Bs[128 * 32];
    const int tid = threadIdx.x;
    const int wave = tid >> 6, lane = tid & 63;
    const int quad = lane >> 4, tl = lane & 15;
    const int m0 = blockIdx.x * 128, n0 = blockIdx.y * 128;
    const int wm = wave >> 1, wn = wave & 1;
    const u16* Bm = blockIdx.z == 0 ? B0 : (blockIdx.z == 1 ? B1 : B2);
    const size_t coff = (size_t)blockIdx.z * M * N;

    f32x4 acc[4][4];
#pragma unroll
    for (int i = 0; i < 4; i++)
#pragma unroll
        for (int j = 0; j < 4; j++) acc[i][j] = (f32x4)(0.0f);

    for (int k0 = 0; k0 < K; k0 += 32) {
        // stage A,B tiles: 512 chunks of 16B each; lane data lands at
        // wave-uniform LDS base + lane*16 (contiguous row-major, no padding)
#pragma unroll
        for (int i = 0; i < 2; i++) {
            int cb = (i * 4 + wave) * 64;
            int ch = cb + lane;
            int row = ch >> 2, c8 = ch & 3;
            async16(A  + (size_t)(m0 + row) * K + k0 + c8 * 8, (u16*)As + cb * 8);
            async16(Bm + (size_t)(n0 + row) * K + k0 + c8 * 8, (u16*)Bs + cb * 8);
        }
        __syncthreads();
        short8 af[4], bg[4];
#pragma unroll
        for (int t = 0; t < 4; t++) {
            af[t] = *(const short8*)&As[(wm * 64 + t * 16 + tl) * 32 + quad * 8];
            bg[t] = *(const short8*)&Bs[(wn * 64 + t * 16 + tl) * 32 + quad * 8];
        }
#pragma unroll
        for (int mt = 0; mt < 4; mt++)
#pragma unroll
            for (int nt = 0; nt < 4; nt++)
                acc[mt][nt] = MFMA(af[mt], bg[nt], acc[mt][nt]);
        __syncthreads();
    }

    // epilogue: C/D layout col=lane&15, row=quad*4+reg
#pragma unroll
    for (int mt = 0; mt < 4; mt++)
#pragma unroll
        for (int nt = 0; nt < 4; nt++)
#pragma unroll
            for (int r = 0; r < 4; r++) {
                int row = m0 + wm * 64 + mt * 16 + quad * 4 + r;
                int col = n0 + wn * 64 + nt * 16 + tl;
                if constexpr (BF16_OUT)
                    ((u16*)Cv)[coff + (size_t)row * N + col] = f2bf(acc[mt][nt][r]);
                else
                    ((float*)Cv)[coff + (size_t)row * N + col] = acc[mt][nt][r];
            }
}

// ---------------- fused windowed attention ----------------
// One block per (b, h, window, half): 64 queries, 192 keys (64 global + 128 local).
// Computes S^T = K q^T so MFMA C-layout in-lane contiguity runs along keys:
// softmax needs only 2 shuffles, P->LDS writes are packed b64.
__global__ __launch_bounds__(256) void attn_win(
    const u16* __restrict__ qkv, u16* __restrict__ outb)
{
    constexpr int T = 8192, D = 1024, HD = 64, G = 64, WIN = 128;
    constexpr int MTOT = 2 * T;
    __shared__ u16 Vt[64 * 200];   // V^T [dim][key], stride 200 (pad 8 -> 2-way free)
    __shared__ u16 Pl[64 * 200];   // P  [query][key], stride 200

    const int blk = blockIdx.x;
    const int half = blk & 1;
    const int nwin = (blk >> 1) & 63;
    const int h = (blk >> 7) & 15;
    const int b = blk >> 11;
    const int tid = threadIdx.x;
    const int wave = tid >> 6, lane = tid & 63;
    const int quad = lane >> 4, tl = lane & 15;
    const int win0 = nwin * WIN;
    const int q0 = win0 + half * 64;
    const size_t brow = (size_t)b * T;
    const u16* qb = qkv;
    const u16* kb = qkv + (size_t)MTOT * D;
    const u16* vb = qkv + (size_t)2 * MTOT * D;

    // stage V transposed: 192 keys x 64 dims -> Vt[dim][key]
    for (int i = 0; i < 6; i++) {
        int ch = i * 256 + tid;        // 1536 chunks of 8 dims
        int r = ch >> 3, c = ch & 7;   // key row, dim chunk
        int tok = r < G ? r : win0 + (r - G);
        ushort8v v = *(const ushort8v*)(vb + (brow + tok) * D + h * HD + c * 8);
#pragma unroll
        for (int j = 0; j < 8; j++) Vt[(c * 8 + j) * 200 + r] = v[j];
    }

    // q fragments (B-operand of S^T): wave's query tile = q0 + wave*16
    short8 bq[2];
    {
        int tok = q0 + wave * 16 + tl;
        const u16* qrow = qb + (brow + tok) * D + h * HD;
        bq[0] = *(const short8*)(qrow + quad * 8);
        bq[1] = *(const short8*)(qrow + 32 + quad * 8);
    }

    __syncthreads();

    // S^T = K q^T : 12 key-tiles x 1 query-tile per wave; K frags direct from global
    f32x4 s[12];
#pragma unroll
    for (int kt = 0; kt < 12; kt++) s[kt] = (f32x4)(0.0f);
#pragma unroll
    for (int kt = 0; kt < 12; kt++) {
        int key = kt * 16 + tl;
        int tok = key < G ? key : win0 + (key - G);
        const u16* krow = kb + (brow + tok) * D + h * HD;
        short8 a0 = *(const short8*)(krow + quad * 8);
        short8 a1 = *(const short8*)(krow + 32 + quad * 8);
        s[kt] = MFMA(a0, bq[0], s[kt]);
        s[kt] = MFMA(a1, bq[1], s[kt]);
    }

    // softmax over keys for query col=tl: in-lane 48 values + 2 quad shuffles
    const float c1 = 0.125f * 1.4426950408889634f;  // scale * log2(e)
    float mx = -1e30f;
#pragma unroll
    for (int kt = 0; kt < 12; kt++)
#pragma unroll
        for (int r = 0; r < 4; r++) mx = fmaxf(mx, s[kt][r]);
    mx = fmaxf(mx, __shfl_xor(mx, 16, 64));
    mx = fmaxf(mx, __shfl_xor(mx, 32, 64));
    float sum = 0.f;
#pragma unroll
    for (int kt = 0; kt < 12; kt++)
#pragma unroll
        for (int r = 0; r < 4; r++) {
            float e = exp2f((s[kt][r] - mx) * c1);
            s[kt][r] = e;
            sum += e;
        }
    sum += __shfl_xor(sum, 16, 64);
    sum += __shfl_xor(sum, 32, 64);
    float inv = 1.f / sum;

    // write P: row = query (wave*16+tl), cols kt*16+quad*4..+3 (b64 packed)
    {
        int lq = wave * 16 + tl;
#pragma unroll
        for (int kt = 0; kt < 12; kt++) {
            ushort4v p;
#pragma unroll
            for (int r = 0; r < 4; r++) p[r] = f2bf(s[kt][r] * inv);
            *(ushort4v*)&Pl[lq * 200 + kt * 16 + quad * 4] = p;
        }
    }
    __syncthreads();

    // out = P V : 1 query-tile x 4 dim-tiles per wave, K=192
    f32x4 o[4];
#pragma unroll
    for (int dt = 0; dt < 4; dt++) o[dt] = (f32x4)(0.0f);
#pragma unroll
    for (int ks = 0; ks < 6; ks++) {
        short8 pa = *(const short8*)&Pl[(wave * 16 + tl) * 200 + ks * 32 + quad * 8];
#pragma unroll
        for (int dt = 0; dt < 4; dt++) {
            short8 vv = *(const short8*)&Vt[(dt * 16 + tl) * 200 + ks * 32 + quad * 8];
            o[dt] = MFMA(pa, vv, o[dt]);
        }
    }

    // epilogue: D[m=query][n=dim], row=quad*4+r, col=tl
#pragma unroll
    for (int dt = 0; dt < 4; dt++)
#pragma unroll
        for (int r = 0; r < 4; r++) {
            int qq = q0 + wave * 16 + quad * 4 + r;
            int dim = dt * 16 + tl;
            outb[(brow + qq) * D + h * HD + dim] = f2bf(o[dt][r]);
        }
}

extern "C" void kernel_launch(void* const* d_in, const int* in_sizes, int n_in,
                              void* d_out, int out_size, void* d_ws, size_t ws_size,
                              hipStream_t stream)
{
    const float* x  = (const float*)d_in[0];
    const float* Wq = (const float*)d_in[1];
    const float* Wk = (const float*)d_in[2];
    const float* Wv = (const float*)d_in[3];
    const float* Wo = (const float*)d_in[4];

    const int M = 16384, D = 1024;   // M = B*T
    u16* xb  = (u16*)d_ws;                  // M*D
    u16* wqb = xb  + (size_t)M * D;         // D*D each
    u16* wkb = wqb + (size_t)D * D;
    u16* wvb = wkb + (size_t)D * D;
    u16* wob = wvb + (size_t)D * D;
    u16* qkv = wob + (size_t)D * D;         // 3*M*D (q,k,v)
    u16* att = qkv + (size_t)3 * M * D;     // M*D

    cvt_bf16<<<2048, 256, 0, stream>>>(x,  xb,  M * D / 4);
    cvt_bf16<<<256,  256, 0, stream>>>(Wq, wqb, D * D / 4);
    cvt_bf16<<<256,  256, 0, stream>>>(Wk, wkb, D * D / 4);
    cvt_bf16<<<256,  256, 0, stream>>>(Wv, wvb, D * D / 4);
    cvt_bf16<<<256,  256, 0, stream>>>(Wo, wob, D * D / 4);

    gemm_nt<true ><<<dim3(M / 128, D / 128, 3), 256, 0, stream>>>(
        xb, wqb, wkb, wvb, qkv, M, D, D);
    attn_win<<<dim3(4096), 256, 0, stream>>>(qkv, att);
    gemm_nt<false><<<dim3(M / 128, D / 128, 1), 256, 0, stream>>>(
        att, wob, wob, wob, d_out, M, D, D);
}

// Round 2
// 377.478 us; speedup vs baseline: 1.0913x; 1.0913x over previous
//
#include <hip/hip_runtime.h>

typedef unsigned short u16;
typedef __attribute__((ext_vector_type(8))) short short8;
typedef __attribute__((ext_vector_type(4))) float f32x4;
typedef __attribute__((ext_vector_type(4))) float floatx4;
typedef __attribute__((ext_vector_type(4))) unsigned short ushort4v;
typedef __attribute__((ext_vector_type(8))) unsigned short ushort8v;

#define MFMA(a, b, c) __builtin_amdgcn_mfma_f32_16x16x32_bf16(a, b, c, 0, 0, 0)

__device__ __forceinline__ u16 f2bf(float f) {
    unsigned u = __float_as_uint(f);
    u += 0x7fffu + ((u >> 16) & 1u);   // RNE
    return (u16)(u >> 16);
}

__device__ __forceinline__ void async16(const void* g, void* l) {
    __builtin_amdgcn_global_load_lds(
        (const __attribute__((address_space(1))) void*)g,
        (__attribute__((address_space(3))) void*)l, 16, 0, 0);
}

// ---------------- fp32 -> bf16 convert, float4 vectorized ----------------
__global__ void cvt_bf16(const float* __restrict__ s, u16* __restrict__ d, int n4) {
    int i = blockIdx.x * blockDim.x + threadIdx.x;
    int stride = gridDim.x * blockDim.x;
    for (; i < n4; i += stride) {
        floatx4 v = ((const floatx4*)s)[i];
        ushort4v o;
        o[0] = f2bf(v[0]); o[1] = f2bf(v[1]); o[2] = f2bf(v[2]); o[3] = f2bf(v[3]);
        ((ushort4v*)d)[i] = o;
    }
}

// convert the 4 weight matrices in one launch (blockIdx.y selects matrix)
__global__ void cvt4_bf16(const float* __restrict__ s0, const float* __restrict__ s1,
                          const float* __restrict__ s2, const float* __restrict__ s3,
                          u16* __restrict__ d, int n4) {
    const float* s = blockIdx.y == 0 ? s0 : (blockIdx.y == 1 ? s1 : (blockIdx.y == 2 ? s2 : s3));
    u16* dd = d + (size_t)blockIdx.y * n4 * 4;
    int i = blockIdx.x * blockDim.x + threadIdx.x;
    int stride = gridDim.x * blockDim.x;
    for (; i < n4; i += stride) {
        floatx4 v = ((const floatx4*)s)[i];
        ushort4v o;
        o[0] = f2bf(v[0]); o[1] = f2bf(v[1]); o[2] = f2bf(v[2]); o[3] = f2bf(v[3]);
        ((ushort4v*)dd)[i] = o;
    }
}

// ---------------- NT GEMM: C[M,N] = A[M,K] * B[N,K]^T (m97 recipe) --------
// 128x128 tile, BK=32, global_load_lds width 16, 2x2 waves, 4x4 acc/wave.
// LDS chunk XOR-swizzle: chunk slot s of row r holds global chunk s^((r>>1)&3)
// -> ds_read_b128 conflicts drop from 8-way to 2-way (free).
template <bool BF16_OUT>
__global__ __launch_bounds__(256) void gemm_nt(
    const u16* __restrict__ A, const u16* __restrict__ B0,
    const u16* __restrict__ B1, const u16* __restrict__ B2,
    void* __restrict__ Cv, int M, int N, int K)
{
    __shared__ u16 As[128 * 32];
    __shared__ u16 Bs[128 * 32];
    const int tid = threadIdx.x;
    const int wave = tid >> 6, lane = tid & 63;
    const int quad = lane >> 4, tl = lane & 15;
    const int m0 = blockIdx.x * 128, n0 = blockIdx.y * 128;
    const int wm = wave >> 1, wn = wave & 1;
    const u16* Bm = blockIdx.z == 0 ? B0 : (blockIdx.z == 1 ? B1 : B2);
    const size_t coff = (size_t)blockIdx.z * M * N;

    f32x4 acc[4][4];
#pragma unroll
    for (int i = 0; i < 4; i++)
#pragma unroll
        for (int j = 0; j < 4; j++) acc[i][j] = (f32x4)(0.0f);

    // reader-side swizzled slot: quad ^ ((tl>>1)&3)  (row-tile offsets are 0 mod 8)
    const int rslot = quad ^ ((tl >> 1) & 3);

    for (int k0 = 0; k0 < K; k0 += 32) {
#pragma unroll
        for (int i = 0; i < 2; i++) {
            int cb = (i * 4 + wave) * 64;
            int ch = cb + lane;
            int row = ch >> 2, slot = ch & 3;
            int g = slot ^ ((row >> 1) & 3);   // global chunk this slot holds
            async16(A  + (size_t)(m0 + row) * K + k0 + g * 8, (u16*)As + cb * 8);
            async16(Bm + (size_t)(n0 + row) * K + k0 + g * 8, (u16*)Bs + cb * 8);
        }
        __syncthreads();
        short8 af[4], bg[4];
#pragma unroll
        for (int t = 0; t < 4; t++) {
            af[t] = *(const short8*)&As[(wm * 64 + t * 16 + tl) * 32 + rslot * 8];
            bg[t] = *(const short8*)&Bs[(wn * 64 + t * 16 + tl) * 32 + rslot * 8];
        }
#pragma unroll
        for (int mt = 0; mt < 4; mt++)
#pragma unroll
            for (int nt = 0; nt < 4; nt++)
                acc[mt][nt] = MFMA(af[mt], bg[nt], acc[mt][nt]);
        __syncthreads();
    }

    // epilogue: C/D layout col=lane&15, row=quad*4+reg
#pragma unroll
    for (int mt = 0; mt < 4; mt++)
#pragma unroll
        for (int nt = 0; nt < 4; nt++)
#pragma unroll
            for (int r = 0; r < 4; r++) {
                int row = m0 + wm * 64 + mt * 16 + quad * 4 + r;
                int col = n0 + wn * 64 + nt * 16 + tl;
                if constexpr (BF16_OUT)
                    ((u16*)Cv)[coff + (size_t)row * N + col] = f2bf(acc[mt][nt][r]);
                else
                    ((float*)Cv)[coff + (size_t)row * N + col] = acc[mt][nt][r];
            }
}

// ---------------- fused windowed attention ----------------
// One block per (b, h, window, half): 64 queries, 192 keys (64 global + 128 local).
// K is staged into LDS via global_load_lds (coalesced, loaded once per block,
// XOR-swizzled 8 chunks/row). The K buffer is aliased with the P buffer.
// S^T = K q^T so MFMA C-layout in-lane contiguity runs along keys.
__global__ __launch_bounds__(256) void attn_win(
    const u16* __restrict__ qkv, u16* __restrict__ outb)
{
    constexpr int T = 8192, D = 1024, HD = 64, G = 64, WIN = 128;
    constexpr int MTOT = 2 * T;
    __shared__ u16 Vt[64 * 200];   // V^T [dim][key], stride 200 (pad 8 -> 2-way free)
    __shared__ u16 KP[12800];      // union: Ks[192][64] (swizzled) then Pl[64][200]

    const int blk = blockIdx.x;
    const int half = blk & 1;
    const int nwin = (blk >> 1) & 63;
    const int h = (blk >> 7) & 15;
    const int b = blk >> 11;
    const int tid = threadIdx.x;
    const int wave = tid >> 6, lane = tid & 63;
    const int quad = lane >> 4, tl = lane & 15;
    const int win0 = nwin * WIN;
    const int q0 = win0 + half * 64;
    const size_t brow = (size_t)b * T;
    const u16* qb = qkv;
    const u16* kb = qkv + (size_t)MTOT * D;
    const u16* vb = qkv + (size_t)2 * MTOT * D;

    // stage K: 192 rows x 8 chunks (16B) = 1536 chunks, swizzled slot = g ^ (row&7)
#pragma unroll
    for (int i = 0; i < 6; i++) {
        int ch = i * 256 + tid;
        int row = ch >> 3, slot = ch & 7;
        int g = slot ^ (row & 7);
        int tok = row < G ? row : win0 + (row - G);
        async16(kb + (brow + tok) * D + h * HD + g * 8,
                (u16*)KP + (i * 256 + wave * 64) * 8);
    }

    // stage V transposed: 192 keys x 64 dims -> Vt[dim][key]
    for (int i = 0; i < 6; i++) {
        int ch = i * 256 + tid;        // 1536 chunks of 8 dims
        int r = ch >> 3, c = ch & 7;   // key row, dim chunk
        int tok = r < G ? r : win0 + (r - G);
        ushort8v v = *(const ushort8v*)(vb + (brow + tok) * D + h * HD + c * 8);
#pragma unroll
        for (int j = 0; j < 8; j++) Vt[(c * 8 + j) * 200 + r] = v[j];
    }

    // q fragments (B-operand of S^T): wave's query tile = q0 + wave*16
    short8 bq[2];
    {
        int tok = q0 + wave * 16 + tl;
        const u16* qrow = qb + (brow + tok) * D + h * HD;
        bq[0] = *(const short8*)(qrow + quad * 8);
        bq[1] = *(const short8*)(qrow + 32 + quad * 8);
    }

    __syncthreads();

    // S^T = K q^T : 12 key-tiles x 1 query-tile per wave, K frags from LDS
    f32x4 s[12];
#pragma unroll
    for (int kt = 0; kt < 12; kt++) s[kt] = (f32x4)(0.0f);
#pragma unroll
    for (int kt = 0; kt < 12; kt++) {
        int row = kt * 16 + tl;
        int s0 = quad ^ (tl & 7);          // chunk quad
        int s1 = (4 + quad) ^ (tl & 7);    // chunk 4+quad
        short8 a0 = *(const short8*)&KP[row * 64 + s0 * 8];
        short8 a1 = *(const short8*)&KP[row * 64 + s1 * 8];
        s[kt] = MFMA(a0, bq[0], s[kt]);
        s[kt] = MFMA(a1, bq[1], s[kt]);
    }

    // softmax over keys for query col=tl: in-lane 48 values + 2 quad shuffles
    const float c1 = 0.125f * 1.4426950408889634f;  // scale * log2(e)
    float mx = -1e30f;
#pragma unroll
    for (int kt = 0; kt < 12; kt++)
#pragma unroll
        for (int r = 0; r < 4; r++) mx = fmaxf(mx, s[kt][r]);
    mx = fmaxf(mx, __shfl_xor(mx, 16, 64));
    mx = fmaxf(mx, __shfl_xor(mx, 32, 64));
    float sum = 0.f;
#pragma unroll
    for (int kt = 0; kt < 12; kt++)
#pragma unroll
        for (int r = 0; r < 4; r++) {
            float e = exp2f((s[kt][r] - mx) * c1);
            s[kt][r] = e;
            sum += e;
        }
    sum += __shfl_xor(sum, 16, 64);
    sum += __shfl_xor(sum, 32, 64);
    float inv = 1.f / sum;

    __syncthreads();   // all waves done reading Ks before P overwrites it

    // write P: row = query (wave*16+tl), cols kt*16+quad*4..+3 (b64 packed)
    u16* Pl = (u16*)KP;
    {
        int lq = wave * 16 + tl;
#pragma unroll
        for (int kt = 0; kt < 12; kt++) {
            ushort4v p;
#pragma unroll
            for (int r = 0; r < 4; r++) p[r] = f2bf(s[kt][r] * inv);
            *(ushort4v*)&Pl[lq * 200 + kt * 16 + quad * 4] = p;
        }
    }
    __syncthreads();

    // out = P V : 1 query-tile x 4 dim-tiles per wave, K=192
    f32x4 o[4];
#pragma unroll
    for (int dt = 0; dt < 4; dt++) o[dt] = (f32x4)(0.0f);
#pragma unroll
    for (int ks = 0; ks < 6; ks++) {
        short8 pa = *(const short8*)&Pl[(wave * 16 + tl) * 200 + ks * 32 + quad * 8];
#pragma unroll
        for (int dt = 0; dt < 4; dt++) {
            short8 vv = *(const short8*)&Vt[(dt * 16 + tl) * 200 + ks * 32 + quad * 8];
            o[dt] = MFMA(pa, vv, o[dt]);
        }
    }

    // epilogue: D[m=query][n=dim], row=quad*4+r, col=tl
#pragma unroll
    for (int dt = 0; dt < 4; dt++)
#pragma unroll
        for (int r = 0; r < 4; r++) {
            int qq = q0 + wave * 16 + quad * 4 + r;
            int dim = dt * 16 + tl;
            outb[(brow + qq) * D + h * HD + dim] = f2bf(o[dt][r]);
        }
}

extern "C" void kernel_launch(void* const* d_in, const int* in_sizes, int n_in,
                              void* d_out, int out_size, void* d_ws, size_t ws_size,
                              hipStream_t stream)
{
    const float* x  = (const float*)d_in[0];
    const float* Wq = (const float*)d_in[1];
    const float* Wk = (const float*)d_in[2];
    const float* Wv = (const float*)d_in[3];
    const float* Wo = (const float*)d_in[4];

    const int M = 16384, D = 1024;   // M = B*T
    u16* xb  = (u16*)d_ws;                  // M*D
    u16* wqb = xb  + (size_t)M * D;         // D*D each (q,k,v,o contiguous)
    u16* wob = wqb + (size_t)3 * D * D;
    u16* qkv = wob + (size_t)D * D;         // 3*M*D (q,k,v)
    u16* att = qkv + (size_t)3 * M * D;     // M*D

    cvt_bf16<<<2048, 256, 0, stream>>>(x, xb, M * D / 4);
    cvt4_bf16<<<dim3(64, 4), 256, 0, stream>>>(Wq, Wk, Wv, Wo, wqb, D * D / 4);

    gemm_nt<true ><<<dim3(M / 128, D / 128, 3), 256, 0, stream>>>(
        xb, wqb, wqb + (size_t)D * D, wqb + (size_t)2 * D * D, qkv, M, D, D);
    attn_win<<<dim3(4096), 256, 0, stream>>>(qkv, att);
    gemm_nt<false><<<dim3(M / 128, D / 128, 1), 256, 0, stream>>>(
        att, wob, wob, wob, d_out, M, D, D);
}

// Round 3
// 339.396 us; speedup vs baseline: 1.2138x; 1.1122x over previous
//
#include <hip/hip_runtime.h>

typedef unsigned short u16;
typedef __attribute__((ext_vector_type(8))) short short8;
typedef __attribute__((ext_vector_type(4))) float f32x4;
typedef __attribute__((ext_vector_type(4))) float floatx4;
typedef __attribute__((ext_vector_type(4))) unsigned short ushort4v;
typedef __attribute__((ext_vector_type(8))) unsigned short ushort8v;

#define MFMA(a, b, c) __builtin_amdgcn_mfma_f32_16x16x32_bf16(a, b, c, 0, 0, 0)

__device__ __forceinline__ u16 f2bf(float f) {
    unsigned u = __float_as_uint(f);
    u += 0x7fffu + ((u >> 16) & 1u);   // RNE
    return (u16)(u >> 16);
}

__device__ __forceinline__ void async16(const void* g, void* l) {
    __builtin_amdgcn_global_load_lds(
        (const __attribute__((address_space(1))) void*)g,
        (__attribute__((address_space(3))) void*)l, 16, 0, 0);
}

// ---------------- fp32 -> bf16 convert, float4 vectorized ----------------
__global__ void cvt_bf16(const float* __restrict__ s, u16* __restrict__ d, int n4) {
    int i = blockIdx.x * blockDim.x + threadIdx.x;
    int stride = gridDim.x * blockDim.x;
    for (; i < n4; i += stride) {
        floatx4 v = ((const floatx4*)s)[i];
        ushort4v o;
        o[0] = f2bf(v[0]); o[1] = f2bf(v[1]); o[2] = f2bf(v[2]); o[3] = f2bf(v[3]);
        ((ushort4v*)d)[i] = o;
    }
}

// convert the 4 weight matrices in one launch (blockIdx.y selects matrix)
__global__ void cvt4_bf16(const float* __restrict__ s0, const float* __restrict__ s1,
                          const float* __restrict__ s2, const float* __restrict__ s3,
                          u16* __restrict__ d, int n4) {
    const float* s = blockIdx.y == 0 ? s0 : (blockIdx.y == 1 ? s1 : (blockIdx.y == 2 ? s2 : s3));
    u16* dd = d + (size_t)blockIdx.y * n4 * 4;
    int i = blockIdx.x * blockDim.x + threadIdx.x;
    int stride = gridDim.x * blockDim.x;
    for (; i < n4; i += stride) {
        floatx4 v = ((const floatx4*)s)[i];
        ushort4v o;
        o[0] = f2bf(v[0]); o[1] = f2bf(v[1]); o[2] = f2bf(v[2]); o[3] = f2bf(v[3]);
        ((ushort4v*)dd)[i] = o;
    }
}

// ---------------- NT GEMM: C[M,N] = A[M,K] * B[N,K]^T ------------------
// 128x128 tile, BK=64 (32 MFMA per barrier pair), global_load_lds width 16,
// 2x2 waves, 4x4 acc/wave. Rows are 8 chunks of 16B; chunk slot s of row r
// holds global chunk s^(r&7) -> ds_read_b128 2-way max (free), async writes
// still cover full 128B rows (coalesced).
template <bool BF16_OUT>
__global__ __launch_bounds__(256) void gemm_nt(
    const u16* __restrict__ A, const u16* __restrict__ B0,
    const u16* __restrict__ B1, const u16* __restrict__ B2,
    void* __restrict__ Cv, int M, int N, int K)
{
    __shared__ u16 As[128 * 64];
    __shared__ u16 Bs[128 * 64];
    const int tid = threadIdx.x;
    const int wave = tid >> 6, lane = tid & 63;
    const int quad = lane >> 4, tl = lane & 15;
    const int m0 = blockIdx.x * 128, n0 = blockIdx.y * 128;
    const int wm = wave >> 1, wn = wave & 1;
    const u16* Bm = blockIdx.z == 0 ? B0 : (blockIdx.z == 1 ? B1 : B2);
    const size_t coff = (size_t)blockIdx.z * M * N;

    f32x4 acc[4][4];
#pragma unroll
    for (int i = 0; i < 4; i++)
#pragma unroll
        for (int j = 0; j < 4; j++) acc[i][j] = (f32x4)(0.0f);

    // per-thread staging chunk (1024 chunks per matrix, 4 instr each)
    const int srow = tid >> 3, sslot = tid & 7;

    for (int k0 = 0; k0 < K; k0 += 64) {
#pragma unroll
        for (int i = 0; i < 4; i++) {
            int row = i * 32 + srow;                 // ch = i*256+tid; row = ch>>3
            int g = sslot ^ (row & 7);               // global chunk held at this slot
            int ldsbase = (i * 256 + wave * 64) * 8; // wave-uniform dest (u16)
            async16(A  + (size_t)(m0 + row) * K + k0 + g * 8, (u16*)As + ldsbase);
            async16(Bm + (size_t)(n0 + row) * K + k0 + g * 8, (u16*)Bs + ldsbase);
        }
        __syncthreads();
#pragma unroll
        for (int h = 0; h < 2; h++) {
            short8 af[4], bg[4];
            const int rs = (((h * 4 + quad) ^ (tl & 7)) * 8);
#pragma unroll
            for (int t = 0; t < 4; t++) {
                af[t] = *(const short8*)&As[(wm * 64 + t * 16 + tl) * 64 + rs];
                bg[t] = *(const short8*)&Bs[(wn * 64 + t * 16 + tl) * 64 + rs];
            }
#pragma unroll
            for (int mt = 0; mt < 4; mt++)
#pragma unroll
                for (int nt = 0; nt < 4; nt++)
                    acc[mt][nt] = MFMA(af[mt], bg[nt], acc[mt][nt]);
        }
        __syncthreads();
    }

    // epilogue: C/D layout col=lane&15, row=quad*4+reg
#pragma unroll
    for (int mt = 0; mt < 4; mt++)
#pragma unroll
        for (int nt = 0; nt < 4; nt++)
#pragma unroll
            for (int r = 0; r < 4; r++) {
                int row = m0 + wm * 64 + mt * 16 + quad * 4 + r;
                int col = n0 + wn * 64 + nt * 16 + tl;
                if constexpr (BF16_OUT)
                    ((u16*)Cv)[coff + (size_t)row * N + col] = f2bf(acc[mt][nt][r]);
                else
                    ((float*)Cv)[coff + (size_t)row * N + col] = acc[mt][nt][r];
            }
}

// ---------------- fused windowed attention ----------------
// One block per (b, h, window, half): 64 queries, 192 keys (64 global + 128 local).
// V is async-staged packed [key][dim] into KP, transposed LDS->LDS into Vt
// (conflict-free b16 reads at bank=lane/2, b128 writes 2-way), then K is
// async-staged into KP (XOR-swizzled). P later reuses KP. S^T = K q^T so
// MFMA C-layout in-lane contiguity runs along keys (2-shuffle softmax).
__global__ __launch_bounds__(256) void attn_win(
    const u16* __restrict__ qkv, u16* __restrict__ outb)
{
    constexpr int T = 8192, D = 1024, HD = 64, G = 64, WIN = 128;
    constexpr int MTOT = 2 * T;
    __shared__ u16 Vt[64 * 200];   // V^T [dim][key], stride 200
    __shared__ u16 KP[12800];      // union: Vs[192][64] -> Ks[192][64] -> Pl[64][200]

    const int blk = blockIdx.x;
    const int half = blk & 1;
    const int nwin = (blk >> 1) & 63;
    const int h = (blk >> 7) & 15;
    const int b = blk >> 11;
    const int tid = threadIdx.x;
    const int wave = tid >> 6, lane = tid & 63;
    const int quad = lane >> 4, tl = lane & 15;
    const int win0 = nwin * WIN;
    const int q0 = win0 + half * 64;
    const size_t brow = (size_t)b * T;
    const u16* qb = qkv;
    const u16* kb = qkv + (size_t)MTOT * D;
    const u16* vb = qkv + (size_t)2 * MTOT * D;

    // phase 1: stage V packed [key][dim] (no swizzle; DMA writes are contiguous)
#pragma unroll
    for (int i = 0; i < 6; i++) {
        int ch = i * 256 + tid;
        int row = ch >> 3, c = ch & 7;
        int tok = row < G ? row : win0 + (row - G);
        async16(vb + (brow + tok) * D + h * HD + c * 8,
                (u16*)KP + (i * 256 + wave * 64) * 8);
    }

    // q fragments (B-operand of S^T): wave's query tile = q0 + wave*16
    short8 bq[2];
    {
        int tok = q0 + wave * 16 + tl;
        const u16* qrow = qb + (brow + tok) * D + h * HD;
        bq[0] = *(const short8*)(qrow + quad * 8);
        bq[1] = *(const short8*)(qrow + 32 + quad * 8);
    }

    __syncthreads();   // V landed

    // phase 2: transpose Vs[key][dim] -> Vt[dim][key]
    // d = lane -> read bank = lane/2 (2-way broadcast, free); b128 write 2-way
    {
        const int d = tid & 63;
#pragma unroll
        for (int i = 0; i < 6; i++) {
            int c = i * 4 + wave;   // key-chunk 0..23
            ushort8v v;
#pragma unroll
            for (int j = 0; j < 8; j++) v[j] = KP[(c * 8 + j) * 64 + d];
            *(ushort8v*)&Vt[d * 200 + c * 8] = v;
        }
    }

    __syncthreads();   // Vt ready, KP free

    // phase 3: stage K into KP, swizzled slot = g ^ (row&7)
#pragma unroll
    for (int i = 0; i < 6; i++) {
        int ch = i * 256 + tid;
        int row = ch >> 3, slot = ch & 7;
        int g = slot ^ (row & 7);
        int tok = row < G ? row : win0 + (row - G);
        async16(kb + (brow + tok) * D + h * HD + g * 8,
                (u16*)KP + (i * 256 + wave * 64) * 8);
    }

    __syncthreads();   // K landed

    // S^T = K q^T : 12 key-tiles x 1 query-tile per wave, K frags from LDS
    f32x4 s[12];
#pragma unroll
    for (int kt = 0; kt < 12; kt++) s[kt] = (f32x4)(0.0f);
#pragma unroll
    for (int kt = 0; kt < 12; kt++) {
        int row = kt * 16 + tl;
        int s0 = quad ^ (tl & 7);
        int s1 = (4 + quad) ^ (tl & 7);
        short8 a0 = *(const short8*)&KP[row * 64 + s0 * 8];
        short8 a1 = *(const short8*)&KP[row * 64 + s1 * 8];
        s[kt] = MFMA(a0, bq[0], s[kt]);
        s[kt] = MFMA(a1, bq[1], s[kt]);
    }

    // softmax over keys for query col=tl: in-lane 48 values + 2 quad shuffles
    const float c1 = 0.125f * 1.4426950408889634f;  // scale * log2(e)
    float mx = -1e30f;
#pragma unroll
    for (int kt = 0; kt < 12; kt++)
#pragma unroll
        for (int r = 0; r < 4; r++) mx = fmaxf(mx, s[kt][r]);
    mx = fmaxf(mx, __shfl_xor(mx, 16, 64));
    mx = fmaxf(mx, __shfl_xor(mx, 32, 64));
    float sum = 0.f;
#pragma unroll
    for (int kt = 0; kt < 12; kt++)
#pragma unroll
        for (int r = 0; r < 4; r++) {
            float e = exp2f((s[kt][r] - mx) * c1);
            s[kt][r] = e;
            sum += e;
        }
    sum += __shfl_xor(sum, 16, 64);
    sum += __shfl_xor(sum, 32, 64);
    float inv = 1.f / sum;

    __syncthreads();   // all waves done reading Ks before P overwrites it

    // write P: row = query (wave*16+tl), cols kt*16+quad*4..+3 (b64 packed)
    u16* Pl = (u16*)KP;
    {
        int lq = wave * 16 + tl;
#pragma unroll
        for (int kt = 0; kt < 12; kt++) {
            ushort4v p;
#pragma unroll
            for (int r = 0; r < 4; r++) p[r] = f2bf(s[kt][r] * inv);
            *(ushort4v*)&Pl[lq * 200 + kt * 16 + quad * 4] = p;
        }
    }
    __syncthreads();

    // out = P V : 1 query-tile x 4 dim-tiles per wave, K=192
    f32x4 o[4];
#pragma unroll
    for (int dt = 0; dt < 4; dt++) o[dt] = (f32x4)(0.0f);
#pragma unroll
    for (int ks = 0; ks < 6; ks++) {
        short8 pa = *(const short8*)&Pl[(wave * 16 + tl) * 200 + ks * 32 + quad * 8];
#pragma unroll
        for (int dt = 0; dt < 4; dt++) {
            short8 vv = *(const short8*)&Vt[(dt * 16 + tl) * 200 + ks * 32 + quad * 8];
            o[dt] = MFMA(pa, vv, o[dt]);
        }
    }

    // epilogue: D[m=query][n=dim], row=quad*4+r, col=tl
#pragma unroll
    for (int dt = 0; dt < 4; dt++)
#pragma unroll
        for (int r = 0; r < 4; r++) {
            int qq = q0 + wave * 16 + quad * 4 + r;
            int dim = dt * 16 + tl;
            outb[(brow + qq) * D + h * HD + dim] = f2bf(o[dt][r]);
        }
}

extern "C" void kernel_launch(void* const* d_in, const int* in_sizes, int n_in,
                              void* d_out, int out_size, void* d_ws, size_t ws_size,
                              hipStream_t stream)
{
    const float* x  = (const float*)d_in[0];
    const float* Wq = (const float*)d_in[1];
    const float* Wk = (const float*)d_in[2];
    const float* Wv = (const float*)d_in[3];
    const float* Wo = (const float*)d_in[4];

    const int M = 16384, D = 1024;   // M = B*T
    u16* xb  = (u16*)d_ws;                  // M*D
    u16* wqb = xb  + (size_t)M * D;         // D*D each (q,k,v,o contiguous)
    u16* wob = wqb + (size_t)3 * D * D;
    u16* qkv = wob + (size_t)D * D;         // 3*M*D (q,k,v)
    u16* att = qkv + (size_t)3 * M * D;     // M*D

    cvt_bf16<<<2048, 256, 0, stream>>>(x, xb, M * D / 4);
    cvt4_bf16<<<dim3(64, 4), 256, 0, stream>>>(Wq, Wk, Wv, Wo, wqb, D * D / 4);

    gemm_nt<true ><<<dim3(M / 128, D / 128, 3), 256, 0, stream>>>(
        xb, wqb, wqb + (size_t)D * D, wqb + (size_t)2 * D * D, qkv, M, D, D);
    attn_win<<<dim3(4096), 256, 0, stream>>>(qkv, att);
    gemm_nt<false><<<dim3(M / 128, D / 128, 1), 256, 0, stream>>>(
        att, wob, wob, wob, d_out, M, D, D);
}